// Round 9
// baseline (118.606 us; speedup 1.0000x reference)
//
#include <hip/hip_runtime.h>
#include <stdint.h>

#define ALPHA 0.2f
#define LOG2E 1.4426950408889634f

typedef unsigned short u16;
typedef short s16x8 __attribute__((ext_vector_type(8)));   // 8 bf16 as shorts
typedef float f32x4 __attribute__((ext_vector_type(4)));

union BF8 { s16x8 v; uint32_t u[4]; u16 s[8]; uint4 q; };

static __device__ __forceinline__ float bf2f(u16 u) {
  union { uint32_t i; float f; } c; c.i = ((uint32_t)u) << 16; return c.f;
}
// round-to-nearest pack of two f32 -> packed bf16x2
static __device__ __forceinline__ uint32_t pk2bf(float lo, float hi) {
  uint32_t ul = __float_as_uint(lo) + 0x8000u;
  uint32_t uh = __float_as_uint(hi) + 0x8000u;
  return (ul >> 16) | (uh & 0xffff0000u);
}

// async global->LDS, 16B per lane; lds dest must be wave-uniform base
static __device__ __forceinline__ void gl2lds16(const void* g, void* l) {
  __builtin_amdgcn_global_load_lds(
      (const __attribute__((address_space(1))) uint32_t*)g,
      (__attribute__((address_space(3))) uint32_t*)l, 16, 0, 0);
}

// ------------- fallback: ws too small -> zero output (diagnostic) --------
__global__ __launch_bounds__(256) void k_zero(uint32_t* __restrict__ out, int n32) {
  int gid = blockIdx.x * 256 + threadIdx.x;
  if (gid < n32) out[gid] = 0u;
}

// ---------------- kernel 1 (fused, wh-FIRST): Wh GEMM + adj-pack ----------
// UNCHANGED from round 8 (best measured).
__global__ __launch_bounds__(256) void k_prep(
    const int* __restrict__ adj, uint32_t* __restrict__ bits,
    const void* __restrict__ hV, const void* __restrict__ WgV,
    const void* __restrict__ aSrcV, const void* __restrict__ aDstV,
    int* __restrict__ flag,
    u16* __restrict__ WhT, float* __restrict__ eS, float* __restrict__ eD) {
  __shared__ __align__(16) char smemRaw[34816];    // WT bf16[128][136] then f32 tile[64][130]
  __shared__ float aS[128], aD[128];

  const int tid = threadIdx.x;
  const int bk = blockIdx.x;

  if (bk >= 256) {            // ---------------- pack role ----------------
    const int pk = bk - 256;
    int base = pk * 256 + tid;
#pragma unroll
    for (int it = 0; it < 8; ++it) {
      int gid = base + it * (2048 * 256);
      unsigned long long m = __ballot(adj[gid] != 0);
      if ((tid & 63) == 0)
        *(unsigned long long*)(&bits[gid >> 5]) = m;
    }
    if (pk == 0 && tid < 64) {   // dtype vote (1=bf16, 0=fp32) for k_attn
      u16 v = ((const u16*)hV)[2 * tid];
      int e = (v >> 7) & 0xff;
      unsigned long long dm = __ballot(e >= 100 && e <= 140);
      if (tid == 0) flag[0] = (__popcll(dm) >= 48) ? 1 : 0;
    }
    return;
  }

  // ---------------- wh role: 64 rows per block ------------
  u16*   WT   = (u16*)smemRaw;
  float* tile = (float*)smemRaw;
  const int mb = bk * 64;

  // wave-local dtype vote (flag not written yet; identical result per wave)
  int isBf;
  {
    u16 v = ((const u16*)hV)[2 * (tid & 63)];
    int e = (v >> 7) & 0xff;
    unsigned long long dm = __ballot(e >= 100 && e <= 140);
    isBf = (__popcll(dm) >= 48) ? 1 : 0;
  }

  if (isBf) {
    const u16* Wg = (const u16*)WgV;
    for (int it = 0; it < 8; ++it) {
      int idx = tid + it * 256;
      int k = idx >> 4, c0 = (idx & 15) * 8;
      uint4 w4 = *(const uint4*)(Wg + (k << 7) + c0);
      u16* wsv = (u16*)&w4;
#pragma unroll
      for (int e = 0; e < 8; ++e) WT[(c0 + e) * 136 + k] = wsv[e];
    }
    if (tid < 128) aS[tid] = bf2f(((const u16*)aSrcV)[tid]);
    else           aD[tid - 128] = bf2f(((const u16*)aDstV)[tid - 128]);
  } else {
    const float* Wg = (const float*)WgV;
    for (int it = 0; it < 8; ++it) {
      int idx = tid + it * 256;
      int k = idx >> 4, c0 = (idx & 15) * 8;
      float4 w0 = *(const float4*)(Wg + (k << 7) + c0);
      float4 w1 = *(const float4*)(Wg + (k << 7) + c0 + 4);
      float wf[8] = {w0.x, w0.y, w0.z, w0.w, w1.x, w1.y, w1.z, w1.w};
#pragma unroll
      for (int e = 0; e < 8; ++e)
        WT[(c0 + e) * 136 + k] = (u16)((__float_as_uint(wf[e]) + 0x8000u) >> 16);
    }
    if (tid < 128) aS[tid] = ((const float*)aSrcV)[tid];
    else           aD[tid - 128] = ((const float*)aDstV)[tid - 128];
  }
  __syncthreads();

  const int wv = tid >> 6, lane = tid & 63, ln = lane & 15, quad = lane >> 4;
  const int row = mb + wv * 16 + ln;

  f32x4 acc[8];
#pragma unroll
  for (int t = 0; t < 8; ++t) acc[t] = (f32x4){0.f, 0.f, 0.f, 0.f};

  if (isBf) {
    const u16* h = (const u16*)hV;
#pragma unroll
    for (int ks = 0; ks < 4; ++ks) {
      s16x8 af = *(const s16x8*)(h + (row << 7) + ks * 32 + quad * 8);
#pragma unroll
      for (int t = 0; t < 8; ++t) {
        s16x8 bfg = *(const s16x8*)(&WT[(t * 16 + ln) * 136 + ks * 32 + quad * 8]);
        acc[t] = __builtin_amdgcn_mfma_f32_16x16x32_bf16(af, bfg, acc[t], 0, 0, 0);
      }
    }
  } else {
    const float* h = (const float*)hV;
#pragma unroll
    for (int ks = 0; ks < 4; ++ks) {
      float4 a0 = *(const float4*)(h + (row << 7) + ks * 32 + quad * 8);
      float4 a1 = *(const float4*)(h + (row << 7) + ks * 32 + quad * 8 + 4);
      BF8 af;
      af.u[0] = pk2bf(a0.x, a0.y);
      af.u[1] = pk2bf(a0.z, a0.w);
      af.u[2] = pk2bf(a1.x, a1.y);
      af.u[3] = pk2bf(a1.z, a1.w);
#pragma unroll
      for (int t = 0; t < 8; ++t) {
        s16x8 bfg = *(const s16x8*)(&WT[(t * 16 + ln) * 136 + ks * 32 + quad * 8]);
        acc[t] = __builtin_amdgcn_mfma_f32_16x16x32_bf16(af.v, bfg, acc[t], 0, 0, 0);
      }
    }
  }
  __syncthreads();                                   // done with WT; reuse as tile

  // D layout: row = quad*4+r, col = t*16+ln
#pragma unroll
  for (int t = 0; t < 8; ++t)
#pragma unroll
    for (int r = 0; r < 4; ++r)
      tile[(wv * 16 + quad * 4 + r) * 130 + t * 16 + ln] = acc[t][r];
  __syncthreads();

  if (tid < 128) {
    int r = tid & 63, grp = tid >> 6;
    const float* a = grp ? aD : aS;
    float sum = 0.f;
#pragma unroll 4
    for (int d = 0; d < 128; ++d) sum += tile[r * 130 + d] * a[d];
    int m = mb + r, b = m >> 11, n = m & 2047;
    (grp ? eD : eS)[(b << 11) + n] = sum * LOG2E;
  }

  // write WhT[b][d][n] (transposed bf16), 64B per thread
  {
    int d = tid >> 1, half = tid & 1;
    int n0 = mb & 2047, b = mb >> 11;
    uint32_t pk[16];
#pragma unroll
    for (int qq = 0; qq < 16; ++qq) {
      float v0 = tile[(half * 32 + 2 * qq) * 130 + d];
      float v1 = tile[(half * 32 + 2 * qq + 1) * 130 + d];
      pk[qq] = pk2bf(v0, v1);
    }
    uint4* dst = (uint4*)(WhT + (size_t)((b << 7) + d) * 2048 + n0 + half * 32);
#pragma unroll
    for (int c = 0; c < 4; ++c)
      dst[c] = make_uint4(pk[c * 4], pk[c * 4 + 1], pk[c * 4 + 2], pk[c * 4 + 3]);
  }
}

// ---------------- kernel 2: masked softmax(rank-1 logits) @ Wh ------------
// R8 structure with ONE change: j-step 64 -> 128. Barriers/block 32 -> 16;
// per-step MFMA work doubles so each gl2lds drain is amortized over 2x
// compute. LDS 40 -> 80 KB (residency unchanged: grid gives 2 blocks/CU).
// grid: 512 = b(8) x ig(64, 32 rows); block 512 thr = 8 waves.
// Swizzle family extended to 256-B rows: 16B granule ^= (d&7), write-side
// via pre-swizzled gl2lds SOURCE, read-side on ds_read (involution).
__global__ __launch_bounds__(512, 4) void k_attn(
    const u16* __restrict__ WhT, const float* __restrict__ eSrc,
    const float* __restrict__ eDst, const uint32_t* __restrict__ adjBits,
    const int* __restrict__ flag, void* __restrict__ outV) {
  __shared__ __align__(16) u16 bufB[2][16384];  // 2 x 32KB  [128 d][128 j]
  __shared__ __align__(16) u16 bufP[2][4096];   // 2 x 8KB   [32 i][128 j]

  const int tid = threadIdx.x;
  // XCD swizzle: b == XCD id -> each XCD L2 holds one WhT[b]
  const int bid = (blockIdx.x & 7) * 64 + (blockIdx.x >> 3);
  const int b = bid >> 6, ig = bid & 63;
  const int i0 = ig * 32;

  const int w = tid >> 6, l = tid & 63;
  const int ln = l & 15, quad = l >> 4;
  const int s = w & 1, dh = w >> 1;

  // ---- staging: 4 gl2lds/wave/step; call c covers rows w*16+c*4..+3 ----
  // lane l -> row d = w*16 + c*4 + (l>>4), phys granule l&15;
  // pre-swizzled source granule = (l&15) ^ (d&7)
  const u16* whtB = WhT + ((size_t)b << 18);
  const int dr = w * 16 + (l >> 4);
  const u16* src0 = whtB + (size_t)(dr +  0) * 2048 + (((l & 15) ^ ((dr +  0) & 7)) * 8);
  const u16* src1 = whtB + (size_t)(dr +  4) * 2048 + (((l & 15) ^ ((dr +  4) & 7)) * 8);
  const u16* src2 = whtB + (size_t)(dr +  8) * 2048 + (((l & 15) ^ ((dr +  8) & 7)) * 8);
  const u16* src3 = whtB + (size_t)(dr + 12) * 2048 + (((l & 15) ^ ((dr + 12) & 7)) * 8);

  // ---- P producer constants: 8 exps/thread/step (one 16B granule) ----
  const int prow = tid >> 4, hg = tid & 15;       // row 0..31, 8-j group 0..15
  const float sSp = eSrc[(b << 11) + i0 + prow];
  const float* eDb = eDst + (b << 11) + hg * 8;
  const uint32_t* adjR = adjBits + (size_t)(i0 + prow) * 64 + (hg >> 2);
  const int mshift = (hg & 3) * 8;
  const int pOff = prow * 256 + ((hg ^ (prow & 7)) * 16);   // bytes

  // ---- consumer LDS offsets (bytes) ----
  const int aBase  = (s * 16 + ln) * 256;
  const int bBase0 = (dh * 32 + ln) * 256;
  const int bBase1 = (dh * 32 + 16 + ln) * 256;
  const int sw0 = ((0 * 4 + quad) ^ (ln & 7)) * 16;
  const int sw1 = ((1 * 4 + quad) ^ (ln & 7)) * 16;
  const int sw2 = ((2 * 4 + quad) ^ (ln & 7)) * 16;
  const int sw3 = ((3 * 4 + quad) ^ (ln & 7)) * 16;

  f32x4 acc0 = (f32x4){0.f, 0.f, 0.f, 0.f};
  f32x4 acc1 = (f32x4){0.f, 0.f, 0.f, 0.f};
  f32x4 accD = (f32x4){0.f, 0.f, 0.f, 0.f};

  BF8 ones;
  ones.u[0] = 0x3f803f80u; ones.u[1] = 0x3f803f80u;
  ones.u[2] = 0x3f803f80u; ones.u[3] = 0x3f803f80u;

#define PPROD(va, vb, mby, pdst)  {                                           \
    float x0 = sSp + (va)[0], x1 = sSp + (va)[1];                             \
    float x2 = sSp + (va)[2], x3 = sSp + (va)[3];                             \
    float x4 = sSp + (vb)[0], x5 = sSp + (vb)[1];                             \
    float x6 = sSp + (vb)[2], x7 = sSp + (vb)[3];                             \
    float p0 = exp2f(__builtin_amdgcn_fmed3f(x0, ALPHA * x0, 80.f));          \
    float p1 = exp2f(__builtin_amdgcn_fmed3f(x1, ALPHA * x1, 80.f));          \
    float p2 = exp2f(__builtin_amdgcn_fmed3f(x2, ALPHA * x2, 80.f));          \
    float p3 = exp2f(__builtin_amdgcn_fmed3f(x3, ALPHA * x3, 80.f));          \
    float p4 = exp2f(__builtin_amdgcn_fmed3f(x4, ALPHA * x4, 80.f));          \
    float p5 = exp2f(__builtin_amdgcn_fmed3f(x5, ALPHA * x5, 80.f));          \
    float p6 = exp2f(__builtin_amdgcn_fmed3f(x6, ALPHA * x6, 80.f));          \
    float p7 = exp2f(__builtin_amdgcn_fmed3f(x7, ALPHA * x7, 80.f));          \
    uint32_t m01 = (((mby) & 1u) ? 0x0000ffffu : 0u) | (((mby) & 2u) ? 0xffff0000u : 0u);  \
    uint32_t m23 = (((mby) & 4u) ? 0x0000ffffu : 0u) | (((mby) & 8u) ? 0xffff0000u : 0u);  \
    uint32_t m45 = (((mby) & 16u) ? 0x0000ffffu : 0u) | (((mby) & 32u) ? 0xffff0000u : 0u);\
    uint32_t m67 = (((mby) & 64u) ? 0x0000ffffu : 0u) | (((mby) & 128u) ? 0xffff0000u : 0u);\
    *(uint4*)((char*)(pdst) + pOff) =                                         \
        make_uint4(pk2bf(p0, p1) & m01, pk2bf(p2, p3) & m23,                  \
                   pk2bf(p4, p5) & m45, pk2bf(p6, p7) & m67);                 \
  }

#define CONSUME(pPc, pBc)  {                                                  \
    s16x8 af0 = *(const s16x8*)((const char*)(pPc) + aBase + sw0);            \
    s16x8 af1 = *(const s16x8*)((const char*)(pPc) + aBase + sw1);            \
    s16x8 af2 = *(const s16x8*)((const char*)(pPc) + aBase + sw2);            \
    s16x8 af3 = *(const s16x8*)((const char*)(pPc) + aBase + sw3);            \
    s16x8 b00 = *(const s16x8*)((const char*)(pBc) + bBase0 + sw0);           \
    s16x8 b01 = *(const s16x8*)((const char*)(pBc) + bBase0 + sw1);           \
    s16x8 b02 = *(const s16x8*)((const char*)(pBc) + bBase0 + sw2);           \
    s16x8 b03 = *(const s16x8*)((const char*)(pBc) + bBase0 + sw3);           \
    s16x8 b10 = *(const s16x8*)((const char*)(pBc) + bBase1 + sw0);           \
    s16x8 b11 = *(const s16x8*)((const char*)(pBc) + bBase1 + sw1);           \
    s16x8 b12 = *(const s16x8*)((const char*)(pBc) + bBase1 + sw2);           \
    s16x8 b13 = *(const s16x8*)((const char*)(pBc) + bBase1 + sw3);           \
    __builtin_amdgcn_s_setprio(1);                                            \
    acc0 = __builtin_amdgcn_mfma_f32_16x16x32_bf16(af0, b00, acc0, 0, 0, 0);  \
    acc1 = __builtin_amdgcn_mfma_f32_16x16x32_bf16(af0, b10, acc1, 0, 0, 0);  \
    acc0 = __builtin_amdgcn_mfma_f32_16x16x32_bf16(af1, b01, acc0, 0, 0, 0);  \
    acc1 = __builtin_amdgcn_mfma_f32_16x16x32_bf16(af1, b11, acc1, 0, 0, 0);  \
    acc0 = __builtin_amdgcn_mfma_f32_16x16x32_bf16(af2, b02, acc0, 0, 0, 0);  \
    acc1 = __builtin_amdgcn_mfma_f32_16x16x32_bf16(af2, b12, acc1, 0, 0, 0);  \
    acc0 = __builtin_amdgcn_mfma_f32_16x16x32_bf16(af3, b03, acc0, 0, 0, 0);  \
    acc1 = __builtin_amdgcn_mfma_f32_16x16x32_bf16(af3, b13, acc1, 0, 0, 0);  \
    if (dh == 0) {                                                            \
      accD = __builtin_amdgcn_mfma_f32_16x16x32_bf16(af0, ones.v, accD, 0, 0, 0); \
      accD = __builtin_amdgcn_mfma_f32_16x16x32_bf16(af1, ones.v, accD, 0, 0, 0); \
      accD = __builtin_amdgcn_mfma_f32_16x16x32_bf16(af2, ones.v, accD, 0, 0, 0); \
      accD = __builtin_amdgcn_mfma_f32_16x16x32_bf16(af3, ones.v, accD, 0, 0, 0); \
    }                                                                         \
    __builtin_amdgcn_s_setprio(0);                                            \
  }

  u16 *bBc = bufB[0], *bBn = bufB[1];
  u16 *bPc = bufP[0], *bPn = bufP[1];

  // ---- prologue: stage tile 0 + produce P0 ----
  gl2lds16(src0, bBc + w * 2048 + 0 * 512);
  gl2lds16(src1, bBc + w * 2048 + 1 * 512);
  gl2lds16(src2, bBc + w * 2048 + 2 * 512);
  gl2lds16(src3, bBc + w * 2048 + 3 * 512);
  {
    f32x4 va = *(const f32x4*)(eDb);
    f32x4 vb = *(const f32x4*)(eDb + 4);
    uint32_t mby = (adjR[0] >> mshift) & 0xffu;
    PPROD(va, vb, mby, bPc);
  }
  __syncthreads();

  for (int t = 0; t < 16; ++t) {
    if (t + 1 < 16) {
      // stage B[t+1] (4 calls, 1KB each)
      gl2lds16(src0 + (size_t)(t + 1) * 128, bBn + w * 2048 + 0 * 512);
      gl2lds16(src1 + (size_t)(t + 1) * 128, bBn + w * 2048 + 1 * 512);
      gl2lds16(src2 + (size_t)(t + 1) * 128, bBn + w * 2048 + 2 * 512);
      gl2lds16(src3 + (size_t)(t + 1) * 128, bBn + w * 2048 + 3 * 512);
      // compute P[t+1]
      f32x4 va = *(const f32x4*)(eDb + (t + 1) * 128);
      f32x4 vb = *(const f32x4*)(eDb + (t + 1) * 128 + 4);
      uint32_t mby = (adjR[(t + 1) * 4] >> mshift) & 0xffu;
      PPROD(va, vb, mby, bPn);
    }
    CONSUME(bPc, bBc);
    __syncthreads();          // next buffers complete; cur reads done
    u16* tb = bBc; bBc = bBn; bBn = tb;
    u16* tp = bPc; bPc = bPn; bPn = tp;
  }

  // ---- epilogue: share denominators via LDS (reuse bufP), normalize ----
  float* den = (float*)bufP;
  if (dh == 0 && ln == 0) {
#pragma unroll
    for (int r = 0; r < 4; ++r) den[s * 16 + quad * 4 + r] = accD[r];
  }
  __syncthreads();

  float inv[4];
#pragma unroll
  for (int r = 0; r < 4; ++r)
    inv[r] = 1.0f / fmaxf(den[s * 16 + quad * 4 + r], 1e-37f);

  const int isBf = *flag;
  if (isBf) {
    u16* outp = (u16*)outV;
#pragma unroll
    for (int tt = 0; tt < 2; ++tt) {
      f32x4 a = tt ? acc1 : acc0;
#pragma unroll
      for (int r = 0; r < 4; ++r) {
        size_t off = ((size_t)((b << 11) + i0 + s * 16 + quad * 4 + r) << 7)
                   + dh * 32 + tt * 16 + ln;
        float v = a[r] * inv[r];
        outp[off] = (u16)((__float_as_uint(v) + 0x8000u) >> 16);
      }
    }
  } else {
    float* outp = (float*)outV;
#pragma unroll
    for (int tt = 0; tt < 2; ++tt) {
      f32x4 a = tt ? acc1 : acc0;
#pragma unroll
      for (int r = 0; r < 4; ++r) {
        size_t off = ((size_t)((b << 11) + i0 + s * 16 + quad * 4 + r) << 7)
                   + dh * 32 + tt * 16 + ln;
        outp[off] = a[r] * inv[r];
      }
    }
  }
#undef PPROD
#undef CONSUME
}

extern "C" void kernel_launch(void* const* d_in, const int* in_sizes, int n_in,
                              void* d_out, int out_size, void* d_ws, size_t ws_size,
                              hipStream_t stream) {
  const void* h   = d_in[0];
  const int* adj  = (const int*)d_in[1];
  const void* Wg  = d_in[2];
  const void* aS  = d_in[3];
  const void* aD  = d_in[4];

  const size_t OFF_ES   = (size_t)4 << 20;               // 4 MB WhT
  const size_t OFF_ED   = OFF_ES + (64 << 10);
  const size_t OFF_BITS = OFF_ED + (64 << 10);
  const size_t OFF_FLAG = OFF_BITS + (512 << 10);
  const size_t NEEDED   = OFF_FLAG + 64;

  if (ws_size < NEEDED) {
    int n32 = out_size / 2;
    k_zero<<<(n32 + 255) / 256, 256, 0, stream>>>((uint32_t*)d_out, n32);
    return;
  }

  char* ws = (char*)d_ws;
  u16* WhT      = (u16*)ws;
  float* eSp    = (float*)(ws + OFF_ES);
  float* eDp    = (float*)(ws + OFF_ED);
  uint32_t* bit = (uint32_t*)(ws + OFF_BITS);
  int* flag     = (int*)(ws + OFF_FLAG);

  // wh role first (blocks 0..255, critical path), pack backfills (256..2303)
  k_prep<<<2304, 256, 0, stream>>>(adj, bit, h, Wg, aS, aD, flag, WhT, eSp, eDp);
  k_attn<<<512, 512, 0, stream>>>(WhT, eSp, eDp, bit, flag, d_out);
}

// Round 10
// 116.403 us; speedup vs baseline: 1.0189x; 1.0189x over previous
//
#include <hip/hip_runtime.h>
#include <stdint.h>

#define ALPHA 0.2f
#define LOG2E 1.4426950408889634f

typedef unsigned short u16;
typedef short s16x8 __attribute__((ext_vector_type(8)));   // 8 bf16 as shorts
typedef float f32x4 __attribute__((ext_vector_type(4)));
typedef float f32x16 __attribute__((ext_vector_type(16)));

union BF8 { s16x8 v; uint32_t u[4]; u16 s[8]; uint4 q; };

static __device__ __forceinline__ float bf2f(u16 u) {
  union { uint32_t i; float f; } c; c.i = ((uint32_t)u) << 16; return c.f;
}
// round-to-nearest pack of two f32 -> packed bf16x2
static __device__ __forceinline__ uint32_t pk2bf(float lo, float hi) {
  uint32_t ul = __float_as_uint(lo) + 0x8000u;
  uint32_t uh = __float_as_uint(hi) + 0x8000u;
  return (ul >> 16) | (uh & 0xffff0000u);
}

// async global->LDS, 16B per lane; lds dest must be wave-uniform base
static __device__ __forceinline__ void gl2lds16(const void* g, void* l) {
  __builtin_amdgcn_global_load_lds(
      (const __attribute__((address_space(1))) uint32_t*)g,
      (__attribute__((address_space(3))) uint32_t*)l, 16, 0, 0);
}

// ------------- fallback: ws too small -> zero output (diagnostic) --------
__global__ __launch_bounds__(256) void k_zero(uint32_t* __restrict__ out, int n32) {
  int gid = blockIdx.x * 256 + threadIdx.x;
  if (gid < n32) out[gid] = 0u;
}

// ---------------- kernel 1 (fused, wh-FIRST): Wh GEMM + adj-pack ----------
// UNCHANGED from round 8 (best measured).
__global__ __launch_bounds__(256) void k_prep(
    const int* __restrict__ adj, uint32_t* __restrict__ bits,
    const void* __restrict__ hV, const void* __restrict__ WgV,
    const void* __restrict__ aSrcV, const void* __restrict__ aDstV,
    int* __restrict__ flag,
    u16* __restrict__ WhT, float* __restrict__ eS, float* __restrict__ eD) {
  __shared__ __align__(16) char smemRaw[34816];    // WT bf16[128][136] then f32 tile[64][130]
  __shared__ float aS[128], aD[128];

  const int tid = threadIdx.x;
  const int bk = blockIdx.x;

  if (bk >= 256) {            // ---------------- pack role ----------------
    const int pk = bk - 256;
    int base = pk * 256 + tid;
#pragma unroll
    for (int it = 0; it < 8; ++it) {
      int gid = base + it * (2048 * 256);
      unsigned long long m = __ballot(adj[gid] != 0);
      if ((tid & 63) == 0)
        *(unsigned long long*)(&bits[gid >> 5]) = m;
    }
    if (pk == 0 && tid < 64) {   // dtype vote (1=bf16, 0=fp32) for k_attn
      u16 v = ((const u16*)hV)[2 * tid];
      int e = (v >> 7) & 0xff;
      unsigned long long dm = __ballot(e >= 100 && e <= 140);
      if (tid == 0) flag[0] = (__popcll(dm) >= 48) ? 1 : 0;
    }
    return;
  }

  // ---------------- wh role: 64 rows per block ------------
  u16*   WT   = (u16*)smemRaw;
  float* tile = (float*)smemRaw;
  const int mb = bk * 64;

  // wave-local dtype vote (flag not written yet; identical result per wave)
  int isBf;
  {
    u16 v = ((const u16*)hV)[2 * (tid & 63)];
    int e = (v >> 7) & 0xff;
    unsigned long long dm = __ballot(e >= 100 && e <= 140);
    isBf = (__popcll(dm) >= 48) ? 1 : 0;
  }

  if (isBf) {
    const u16* Wg = (const u16*)WgV;
    for (int it = 0; it < 8; ++it) {
      int idx = tid + it * 256;
      int k = idx >> 4, c0 = (idx & 15) * 8;
      uint4 w4 = *(const uint4*)(Wg + (k << 7) + c0);
      u16* wsv = (u16*)&w4;
#pragma unroll
      for (int e = 0; e < 8; ++e) WT[(c0 + e) * 136 + k] = wsv[e];
    }
    if (tid < 128) aS[tid] = bf2f(((const u16*)aSrcV)[tid]);
    else           aD[tid - 128] = bf2f(((const u16*)aDstV)[tid - 128]);
  } else {
    const float* Wg = (const float*)WgV;
    for (int it = 0; it < 8; ++it) {
      int idx = tid + it * 256;
      int k = idx >> 4, c0 = (idx & 15) * 8;
      float4 w0 = *(const float4*)(Wg + (k << 7) + c0);
      float4 w1 = *(const float4*)(Wg + (k << 7) + c0 + 4);
      float wf[8] = {w0.x, w0.y, w0.z, w0.w, w1.x, w1.y, w1.z, w1.w};
#pragma unroll
      for (int e = 0; e < 8; ++e)
        WT[(c0 + e) * 136 + k] = (u16)((__float_as_uint(wf[e]) + 0x8000u) >> 16);
    }
    if (tid < 128) aS[tid] = ((const float*)aSrcV)[tid];
    else           aD[tid - 128] = ((const float*)aDstV)[tid - 128];
  }
  __syncthreads();

  const int wv = tid >> 6, lane = tid & 63, ln = lane & 15, quad = lane >> 4;
  const int row = mb + wv * 16 + ln;

  f32x4 acc[8];
#pragma unroll
  for (int t = 0; t < 8; ++t) acc[t] = (f32x4){0.f, 0.f, 0.f, 0.f};

  if (isBf) {
    const u16* h = (const u16*)hV;
#pragma unroll
    for (int ks = 0; ks < 4; ++ks) {
      s16x8 af = *(const s16x8*)(h + (row << 7) + ks * 32 + quad * 8);
#pragma unroll
      for (int t = 0; t < 8; ++t) {
        s16x8 bfg = *(const s16x8*)(&WT[(t * 16 + ln) * 136 + ks * 32 + quad * 8]);
        acc[t] = __builtin_amdgcn_mfma_f32_16x16x32_bf16(af, bfg, acc[t], 0, 0, 0);
      }
    }
  } else {
    const float* h = (const float*)hV;
#pragma unroll
    for (int ks = 0; ks < 4; ++ks) {
      float4 a0 = *(const float4*)(h + (row << 7) + ks * 32 + quad * 8);
      float4 a1 = *(const float4*)(h + (row << 7) + ks * 32 + quad * 8 + 4);
      BF8 af;
      af.u[0] = pk2bf(a0.x, a0.y);
      af.u[1] = pk2bf(a0.z, a0.w);
      af.u[2] = pk2bf(a1.x, a1.y);
      af.u[3] = pk2bf(a1.z, a1.w);
#pragma unroll
      for (int t = 0; t < 8; ++t) {
        s16x8 bfg = *(const s16x8*)(&WT[(t * 16 + ln) * 136 + ks * 32 + quad * 8]);
        acc[t] = __builtin_amdgcn_mfma_f32_16x16x32_bf16(af.v, bfg, acc[t], 0, 0, 0);
      }
    }
  }
  __syncthreads();                                   // done with WT; reuse as tile

  // D layout: row = quad*4+r, col = t*16+ln
#pragma unroll
  for (int t = 0; t < 8; ++t)
#pragma unroll
    for (int r = 0; r < 4; ++r)
      tile[(wv * 16 + quad * 4 + r) * 130 + t * 16 + ln] = acc[t][r];
  __syncthreads();

  if (tid < 128) {
    int r = tid & 63, grp = tid >> 6;
    const float* a = grp ? aD : aS;
    float sum = 0.f;
#pragma unroll 4
    for (int d = 0; d < 128; ++d) sum += tile[r * 130 + d] * a[d];
    int m = mb + r, b = m >> 11, n = m & 2047;
    (grp ? eD : eS)[(b << 11) + n] = sum * LOG2E;
  }

  // write WhT[b][d][n] (transposed bf16), 64B per thread
  {
    int d = tid >> 1, half = tid & 1;
    int n0 = mb & 2047, b = mb >> 11;
    uint32_t pk[16];
#pragma unroll
    for (int qq = 0; qq < 16; ++qq) {
      float v0 = tile[(half * 32 + 2 * qq) * 130 + d];
      float v1 = tile[(half * 32 + 2 * qq + 1) * 130 + d];
      pk[qq] = pk2bf(v0, v1);
    }
    uint4* dst = (uint4*)(WhT + (size_t)((b << 7) + d) * 2048 + n0 + half * 32);
#pragma unroll
    for (int c = 0; c < 4; ++c)
      dst[c] = make_uint4(pk[c * 4], pk[c * 4 + 1], pk[c * 4 + 2], pk[c * 4 + 3]);
  }
}

// ---------------- kernel 2: masked softmax(rank-1 logits) @ Wh ------------
// R2/R8 pipeline skeleton (coop P, 2-deep gl2lds dbuf, 1 barrier/step) with
// the MFMA switched to 32x32x16 (2x arithmetic intensity per LDS byte).
// Waves = dh(4: 32-d cols) x jh(2: j-half); each wave owns ONE 32x32 output
// tile -> B-frag dup 1 (was 2), 4 ds_reads/thread/step (was 6), 16 MFMA
// issues/block-step (was 40). jh-partials merged once via LDS (bufB reuse).
// Denominator: R5-proven in-register dsum of bf16-rounded P.
// grid: 512 = b(8) x ig(64, 32 rows); block 512 thr = 8 waves; LDS 40KB.
__global__ __launch_bounds__(512, 4) void k_attn(
    const u16* __restrict__ WhT, const float* __restrict__ eSrc,
    const float* __restrict__ eDst, const uint32_t* __restrict__ adjBits,
    const int* __restrict__ flag, void* __restrict__ outV) {
  __shared__ __align__(16) u16 bufB[2][8192];   // 2 x 16KB  [128 d][64 j]
  __shared__ __align__(16) u16 bufP[2][2048];   // 2 x 4KB   [32 i][64 j]
  __shared__ float den[32];

  const int tid = threadIdx.x;
  // XCD swizzle: b == XCD id -> each XCD L2 holds one WhT[b]
  const int bid = (blockIdx.x & 7) * 64 + (blockIdx.x >> 3);
  const int b = bid >> 6, ig = bid & 63;
  const int i0 = ig * 32;

  const int w = tid >> 6, l = tid & 63;
  const int dh = w & 3, jh = w >> 2;
  const int lh = l >> 5;                 // lane half (k-subrange)
  const int xk = l & 7;                  // XOR swizzle key (== row&7 below)

  // ---- staging constants (B tile) — R2 verbatim ----
  const int gsrc = (l & 7) ^ ((l >> 3) & 7);
  const u16* whtB = WhT + ((size_t)b << 18);
  const u16* srcB = whtB + (size_t)(w * 8 + (l >> 3)) * 2048 + gsrc * 8;

  // ---- P producer constants — R2/R5 verbatim ----
  const int prow = tid >> 4, hg = tid & 15;       // row 0..31, 4-j group 0..15
  const float sSp = eSrc[(b << 11) + i0 + prow];
  const float* eDb = eDst + (b << 11) + hg * 4;
  const uint32_t* adjB = adjBits + (size_t)(i0 + prow) * 64 + (hg >> 3);
  const int pOff = prow * 128 + ((hg ^ ((prow & 7) << 1)) * 8);   // bytes
  float dsum = 0.f;

  // ---- consumer LDS offsets (bytes): 32x32x16 fragments ----
  // A: lane l holds P[row=l&31][k=(l>>5)*8..+8]; B: WhT[col=dh*32+(l&31)][same k]
  const int aOff0 = (l & 31) * 128 + (((jh * 4 + 0 + lh) ^ xk) * 16);
  const int aOff1 = (l & 31) * 128 + (((jh * 4 + 2 + lh) ^ xk) * 16);
  const int bOff0 = (dh * 32 + (l & 31)) * 128 + (((jh * 4 + 0 + lh) ^ xk) * 16);
  const int bOff1 = (dh * 32 + (l & 31)) * 128 + (((jh * 4 + 2 + lh) ^ xk) * 16);

  f32x16 acc;
#pragma unroll
  for (int r = 0; r < 16; ++r) acc[r] = 0.f;

  // produce P tile (masked exp bf16), accumulate bf16-rounded row-sum
#define PPROD(dv, aw, pdst) {                                                 \
    uint32_t nib = ((aw) >> ((hg & 7) * 4)) & 0xfu;                           \
    float x0 = sSp + (dv)[0], x1 = sSp + (dv)[1];                             \
    float x2 = sSp + (dv)[2], x3 = sSp + (dv)[3];                             \
    float p0 = exp2f(__builtin_amdgcn_fmed3f(x0, ALPHA * x0, 80.f));          \
    float p1 = exp2f(__builtin_amdgcn_fmed3f(x1, ALPHA * x1, 80.f));          \
    float p2 = exp2f(__builtin_amdgcn_fmed3f(x2, ALPHA * x2, 80.f));          \
    float p3 = exp2f(__builtin_amdgcn_fmed3f(x3, ALPHA * x3, 80.f));          \
    p0 = (nib & 1u) ? p0 : 0.f;                                               \
    p1 = (nib & 2u) ? p1 : 0.f;                                               \
    p2 = (nib & 4u) ? p2 : 0.f;                                               \
    p3 = (nib & 8u) ? p3 : 0.f;                                               \
    uint32_t w0 = pk2bf(p0, p1), w1 = pk2bf(p2, p3);                          \
    dsum += __uint_as_float(w0 << 16) + __uint_as_float(w0 & 0xffff0000u)     \
          + __uint_as_float(w1 << 16) + __uint_as_float(w1 & 0xffff0000u);    \
    *(uint2*)((char*)(pdst) + pOff) = make_uint2(w0, w1);                     \
  }

  u16 *bBc = bufB[0], *bBn = bufB[1];
  u16 *bPc = bufP[0], *bPn = bufP[1];

  // ---- prologue: stage tile 0 + produce P0 ----
  gl2lds16(srcB, bBc + w * 512);
  gl2lds16(srcB + 131072, bBc + 4096 + w * 512);
  {
    f32x4 dv = *(const f32x4*)(eDb);
    uint32_t aw = adjB[0];
    PPROD(dv, aw, bPc);
  }
  __syncthreads();

  for (int t = 0; t < 32; ++t) {
    if (t + 1 < 32) {
      // stage B[t+1]
      gl2lds16(srcB + (size_t)(t + 1) * 64, bBn + w * 512);
      gl2lds16(srcB + (size_t)(t + 1) * 64 + 131072, bBn + 4096 + w * 512);
      // compute P[t+1]
      f32x4 dv = *(const f32x4*)(eDb + (t + 1) * 64);
      uint32_t aw = adjB[(t + 1) * 2];
      PPROD(dv, aw, bPn);
    }
    // consume tile t: 2 k-slices of the wave's j-half
    {
      s16x8 a0 = *(const s16x8*)((const char*)bPc + aOff0);
      s16x8 a1 = *(const s16x8*)((const char*)bPc + aOff1);
      s16x8 f0 = *(const s16x8*)((const char*)bBc + bOff0);
      s16x8 f1 = *(const s16x8*)((const char*)bBc + bOff1);
      __builtin_amdgcn_s_setprio(1);
      acc = __builtin_amdgcn_mfma_f32_32x32x16_bf16(a0, f0, acc, 0, 0, 0);
      acc = __builtin_amdgcn_mfma_f32_32x32x16_bf16(a1, f1, acc, 0, 0, 0);
      __builtin_amdgcn_s_setprio(0);
    }
    __syncthreads();          // next buffers complete; cur reads done
    u16* tb = bBc; bBc = bBn; bBn = tb;
    u16* tp = bPc; bPc = bPn; bPn = tp;
  }

  // ---- epilogue: den reduce, jh-merge via LDS (bufB reuse), store ----
  {
#pragma unroll
    for (int m = 1; m < 16; m <<= 1) dsum += __shfl_xor(dsum, m);
    if ((tid & 15) == 0) den[prow] = dsum;
  }
  float* mrg = (float*)bufB;    // 4 dh x 16 reg x 64 lanes = 16 KB
  if (jh == 1) {
#pragma unroll
    for (int r = 0; r < 16; ++r) mrg[dh * 1024 + r * 64 + l] = acc[r];
  }
  __syncthreads();

  if (jh == 0) {
    const int isBf = *flag;
    const int col = dh * 32 + (l & 31);
    if (isBf) {
      u16* outp = (u16*)outV;
#pragma unroll
      for (int r = 0; r < 16; ++r) {
        int irow = (r & 3) + 8 * (r >> 2) + 4 * lh;
        float v = acc[r] + mrg[dh * 1024 + r * 64 + l];
        v *= 1.0f / fmaxf(den[irow], 1e-37f);
        size_t off = ((size_t)((b << 11) + i0 + irow) << 7) + col;
        outp[off] = (u16)((__float_as_uint(v) + 0x8000u) >> 16);
      }
    } else {
      float* outp = (float*)outV;
#pragma unroll
      for (int r = 0; r < 16; ++r) {
        int irow = (r & 3) + 8 * (r >> 2) + 4 * lh;
        float v = acc[r] + mrg[dh * 1024 + r * 64 + l];
        v *= 1.0f / fmaxf(den[irow], 1e-37f);
        size_t off = ((size_t)((b << 11) + i0 + irow) << 7) + col;
        outp[off] = v;
      }
    }
  }
#undef PPROD
}

extern "C" void kernel_launch(void* const* d_in, const int* in_sizes, int n_in,
                              void* d_out, int out_size, void* d_ws, size_t ws_size,
                              hipStream_t stream) {
  const void* h   = d_in[0];
  const int* adj  = (const int*)d_in[1];
  const void* Wg  = d_in[2];
  const void* aS  = d_in[3];
  const void* aD  = d_in[4];

  const size_t OFF_ES   = (size_t)4 << 20;               // 4 MB WhT
  const size_t OFF_ED   = OFF_ES + (64 << 10);
  const size_t OFF_BITS = OFF_ED + (64 << 10);
  const size_t OFF_FLAG = OFF_BITS + (512 << 10);
  const size_t NEEDED   = OFF_FLAG + 64;

  if (ws_size < NEEDED) {
    int n32 = out_size / 2;
    k_zero<<<(n32 + 255) / 256, 256, 0, stream>>>((uint32_t*)d_out, n32);
    return;
  }

  char* ws = (char*)d_ws;
  u16* WhT      = (u16*)ws;
  float* eSp    = (float*)(ws + OFF_ES);
  float* eDp    = (float*)(ws + OFF_ED);
  uint32_t* bit = (uint32_t*)(ws + OFF_BITS);
  int* flag     = (int*)(ws + OFF_FLAG);

  // wh role first (blocks 0..255, critical path), pack backfills (256..2303)
  k_prep<<<2304, 256, 0, stream>>>(adj, bit, h, Wg, aS, aD, flag, WhT, eSp, eDp);
  k_attn<<<512, 512, 0, stream>>>(WhT, eSp, eDp, bit, flag, d_out);
}